// Round 10
// baseline (1360.434 us; speedup 1.0000x reference)
//
#include <hip/hip_runtime.h>
#include <math.h>

#define N_TOK 131072
#define DIM   64
#define QS    8
#define KS    1024

typedef _Float16 f16x8 __attribute__((ext_vector_type(8)));
typedef float    f32x4 __attribute__((ext_vector_type(4)));

#define RSCALE   2048.0f
#define RISCALE  4.8828125e-4f   // 2^-11

// split fp32 v into f16 limbs + scaled-hi: v ~= hi + lo*2^-11 ; hs = 2048*hi (exact)
#define SPLIT3(v, hi, lo, hs) { _Float16 _h = (_Float16)(v); (hi) = _h;        \
                                (lo) = (_Float16)(((v) - (float)_h) * RSCALE); \
                                (hs) = (_Float16)((float)_h * RSCALE); }

// ---- workspace layout G: 512 minis of 16 codewords, stride 4160 B:
//   [0   .. 4095]  frag limbs: 4 sub-slots of 1KB ({h0,h1,l0,l1} = limb*2+half)
//   [4096.. 4159]  16 floats: -1024*||c||^2 seeds for the mini's 16 codewords
// Mini g: stage q = g>>6, wave w = (g>>5)&1, t = g&31 -> cw w*512+t*16 .. +15.
// (The staged seed load reads 256B from +4096, overrunning 192B into the next
//  mini -- harmless garbage in LDS lanes 16-63, never read.)
#define MINI_B     4160
#define MINI_LDS_H 2176     // halves per LDS mini buffer (4096 frag + 256 seed)
#define SEED_H     2048     // half-offset of seed region in LDS buffer

// ---- pre-pass 1: codebook -> f16 limbs in MFMA A-fragment order.
// slot = mini*4 + sub; sub = limb*2 + half. Frag: [cw=lane&15][k=half*32+quad*8+j].
__global__ void conv_kernel(const float* __restrict__ cb, _Float16* __restrict__ G) {
    int t = blockIdx.x * blockDim.x + threadIdx.x;
    if (t >= 2048 * 64) return;
    const int lane = t & 63, slot = t >> 6;
    const int mini = slot >> 2, sub = slot & 3;
    const int h = sub & 1, l = sub >> 1;
    const int q = mini >> 6, idx = mini & 63, w = idx >> 5, tt = idx & 31;
    const int cw = w * 512 + tt * 16 + (lane & 15);
    const int d0 = h * 32 + (lane >> 4) * 8;
    const float* src = cb + ((size_t)q * KS + cw) * DIM + d0;
    f16x8 v;
#pragma unroll
    for (int j = 0; j < 8; ++j) {
        float c = src[j];
        _Float16 hi = (_Float16)c;
        v[j] = (l == 0) ? hi : (_Float16)((c - (float)hi) * RSCALE);
    }
    *(f16x8*)(G + (size_t)mini * 2080 + sub * 512 + lane * 8) = v;
}

// ---- pre-pass 2: dc2 seeds into each mini's tail ----
__global__ void dc2_kernel(const float* __restrict__ cb, float* __restrict__ Gf) {
    int i = blockIdx.x * blockDim.x + threadIdx.x;
    if (i < QS * KS) {
        const float* c = cb + (size_t)i * DIM;
        float s = 0.f;
#pragma unroll
        for (int d = 0; d < DIM; ++d) s = fmaf(c[d], c[d], s);
        const int q = i >> 10, k = i & 1023;
        const int w = k >> 9, tt = (k >> 4) & 31, j = k & 15;
        const int mini = q * 64 + w * 32 + tt;
        Gf[(size_t)mini * 1040 + 1024 + j] = -1024.0f * s;
    }
}

// ---- main: CODEBOOK-SPLIT 2-wave blocks. 2048 blocks x 128 thr; both waves
// hold the SAME 64 tokens (4 sets, r6 reuse); wave w scans cw [w*512,(w+1)*512)
// per stage via private double-buffered 16-cw minis (counted vmcnt(5), no
// intra-loop barriers). 16 waves/CU = 4 waves/SIMD -- doubles the per-SIMD MFMA
// duty sum (2x25% -> 4x25%) that capped r8/r9 at 50% MfmaUtil. Per stage: one
// cross-wave argmin merge (parity-buffered LDS exchange + 1 raw barrier); both
// waves then do identical residual updates so limb registers stay coherent.
__global__ __launch_bounds__(128, 4)
void rvq_mfma_kernel(const float* __restrict__ x,
                     const float* __restrict__ cbf,
                     const _Float16* __restrict__ F,
                     float* __restrict__ out) {
    __shared__ __attribute__((aligned(16))) _Float16 smem[2][2][MINI_LDS_H]; // 17408 B
    __shared__ float mrgv[2][2][64];   // [parity][wave][token] 1024 B
    __shared__ int   mrgi[2][2][64];   // 1024 B

    const int tid  = threadIdx.x;
    const int wave = tid >> 6;
    const int lane = tid & 63;
    const int quad = lane >> 4;
    const int m    = lane & 15;
    const int quad4 = quad * 4;

    const int tokenBase = blockIdx.x * 64;   // both waves: same 64 tokens

    // token limbs, 4 sets (B-frag layout): th = hi, tl = 2048*(r-hi), ts = 2048*hi
    f16x8 th00, th01, tl00, tl01, ts00, ts01;
    f16x8 th10, th11, tl10, tl11, ts10, ts11;
    f16x8 th20, th21, tl20, tl21, ts20, ts21;
    f16x8 th30, th31, tl30, tl31, ts30, ts31;

#define LOADTOK(S, TH0, TH1, TL0, TL1, TS0, TS1) {                                \
        const float* xa = x + (size_t)(tokenBase + (S) * 16 + m) * DIM + quad * 8;\
        f32x4 a0 = *(const f32x4*)(xa);                                           \
        f32x4 a1 = *(const f32x4*)(xa + 4);                                       \
        f32x4 a2 = *(const f32x4*)(xa + 32);                                      \
        f32x4 a3 = *(const f32x4*)(xa + 36);                                      \
        _Pragma("unroll")                                                         \
        for (int j = 0; j < 4; ++j) {                                             \
            SPLIT3(a0[j], TH0[j],   TL0[j],   TS0[j]);                            \
            SPLIT3(a1[j], TH0[j+4], TL0[j+4], TS0[j+4]);                          \
            SPLIT3(a2[j], TH1[j],   TL1[j],   TS1[j]);                            \
            SPLIT3(a3[j], TH1[j+4], TL1[j+4], TS1[j+4]);                          \
        }                                                                         \
    }
    LOADTOK(0, th00, th01, tl00, tl01, ts00, ts01);
    LOADTOK(1, th10, th11, tl10, tl11, ts10, ts11);
    LOADTOK(2, th20, th21, tl20, tl21, ts20, ts21);
    LOADTOK(3, th30, th31, tl30, tl31, ts30, ts31);

// stage one 16-cw mini (4KB frags + seed) into this wave's LDS buffer BUF.
// 5 vmem ops total.
#define STAGE(GC, BUF) {                                                          \
        const char* _gs = (const char*)F + (size_t)(GC) * MINI_B + (lane << 4);   \
        _Float16* _ld = &smem[wave][BUF][0];                                      \
        _Pragma("unroll")                                                         \
        for (int _j = 0; _j < 4; ++_j)                                            \
            __builtin_amdgcn_global_load_lds(                                     \
                (const __attribute__((address_space(1))) void*)(_gs + _j * 1024), \
                (__attribute__((address_space(3))) void*)(_ld + _j * 512),        \
                16, 0, 0);                                                        \
        __builtin_amdgcn_global_load_lds(                                         \
            (const __attribute__((address_space(1))) void*)((const char*)F        \
                + (size_t)(GC) * MINI_B + 4096 + (lane << 2)),                    \
            (__attribute__((address_space(3))) void*)(_ld + SEED_H),              \
            4, 0, 0);                                                             \
    }

// One 16-cw group: 24 MFMAs = 4 independent depth-6 chains (one per token-set),
// all sharing the codeword fragments. acc IS the scaled score.
#define COMPUTE(CH0, CH1, CL0, CL1, CIV, CWB) {                                     \
        __builtin_amdgcn_s_setprio(1);                                              \
        f32x4 A0 = __builtin_amdgcn_mfma_f32_16x16x32_f16(CH0, ts00, CIV, 0,0,0);   \
        f32x4 A1 = __builtin_amdgcn_mfma_f32_16x16x32_f16(CH0, ts10, CIV, 0,0,0);   \
        f32x4 A2 = __builtin_amdgcn_mfma_f32_16x16x32_f16(CH0, ts20, CIV, 0,0,0);   \
        f32x4 A3 = __builtin_amdgcn_mfma_f32_16x16x32_f16(CH0, ts30, CIV, 0,0,0);   \
        A0 = __builtin_amdgcn_mfma_f32_16x16x32_f16(CH1, ts01, A0, 0,0,0);          \
        A1 = __builtin_amdgcn_mfma_f32_16x16x32_f16(CH1, ts11, A1, 0,0,0);          \
        A2 = __builtin_amdgcn_mfma_f32_16x16x32_f16(CH1, ts21, A2, 0,0,0);          \
        A3 = __builtin_amdgcn_mfma_f32_16x16x32_f16(CH1, ts31, A3, 0,0,0);          \
        A0 = __builtin_amdgcn_mfma_f32_16x16x32_f16(CL0, th00, A0, 0,0,0);          \
        A1 = __builtin_amdgcn_mfma_f32_16x16x32_f16(CL0, th10, A1, 0,0,0);          \
        A2 = __builtin_amdgcn_mfma_f32_16x16x32_f16(CL0, th20, A2, 0,0,0);          \
        A3 = __builtin_amdgcn_mfma_f32_16x16x32_f16(CL0, th30, A3, 0,0,0);          \
        A0 = __builtin_amdgcn_mfma_f32_16x16x32_f16(CL1, th01, A0, 0,0,0);          \
        A1 = __builtin_amdgcn_mfma_f32_16x16x32_f16(CL1, th11, A1, 0,0,0);          \
        A2 = __builtin_amdgcn_mfma_f32_16x16x32_f16(CL1, th21, A2, 0,0,0);          \
        A3 = __builtin_amdgcn_mfma_f32_16x16x32_f16(CL1, th31, A3, 0,0,0);          \
        A0 = __builtin_amdgcn_mfma_f32_16x16x32_f16(CH0, tl00, A0, 0,0,0);          \
        A1 = __builtin_amdgcn_mfma_f32_16x16x32_f16(CH0, tl10, A1, 0,0,0);          \
        A2 = __builtin_amdgcn_mfma_f32_16x16x32_f16(CH0, tl20, A2, 0,0,0);          \
        A3 = __builtin_amdgcn_mfma_f32_16x16x32_f16(CH0, tl30, A3, 0,0,0);          \
        A0 = __builtin_amdgcn_mfma_f32_16x16x32_f16(CH1, tl01, A0, 0,0,0);          \
        A1 = __builtin_amdgcn_mfma_f32_16x16x32_f16(CH1, tl11, A1, 0,0,0);          \
        A2 = __builtin_amdgcn_mfma_f32_16x16x32_f16(CH1, tl21, A2, 0,0,0);          \
        A3 = __builtin_amdgcn_mfma_f32_16x16x32_f16(CH1, tl31, A3, 0,0,0);          \
        __builtin_amdgcn_s_setprio(0);                                              \
        const int base = (CWB) + quad4;                                             \
        _Pragma("unroll")                                                           \
        for (int i = 0; i < 4; ++i) {                                               \
            if (A0[i] > bv0) { bv0 = A0[i]; bi0 = base + i; }                       \
            if (A1[i] > bv1) { bv1 = A1[i]; bi1 = base + i; }                       \
            if (A2[i] > bv2) { bv2 = A2[i]; bi2 = base + i; }                       \
            if (A3[i] > bv3) { bv3 = A3[i]; bi3 = base + i; }                       \
        }                                                                           \
    }

    // prologue: stage this wave's first mini of stage 0
    STAGE(wave * 32, 0);
    int cur = 0;

    for (int q = 0; q < QS; ++q) {
        const float* cfq = cbf + (size_t)q * KS * DIM;

        float bv0 = -INFINITY, bv1 = -INFINITY, bv2 = -INFINITY, bv3 = -INFINITY;
        int   bi0 = 0, bi1 = 0, bi2 = 0, bi3 = 0;

        for (int t = 0; t < 32; ++t) {
            int nxt = (t < 31) ? (q * 64 + wave * 32 + t + 1)
                    : (q < 7)  ? ((q + 1) * 64 + wave * 32) : -1;
            if (nxt >= 0) {
                STAGE(nxt, cur ^ 1);   // 5 vmem ops
                // wait until only the 5 just-issued remain -> current mini
                // (and everything older) resident. Never drains the prefetch.
                asm volatile("s_waitcnt vmcnt(5)" ::: "memory");
            } else {
                asm volatile("s_waitcnt vmcnt(0)" ::: "memory");
            }
            __builtin_amdgcn_sched_barrier(0);

            const _Float16* L   = &smem[wave][cur][0] + lane * 8;
            const float*    dcL = (const float*)(&smem[wave][cur][SEED_H]);

            f32x4 ci = *(const f32x4*)(dcL + quad4);
            f16x8 h0 = *(const f16x8*)(L);
            f16x8 h1 = *(const f16x8*)(L + 512);
            f16x8 l0 = *(const f16x8*)(L + 1024);
            f16x8 l1 = *(const f16x8*)(L + 1536);

            COMPUTE(h0, h1, l0, l1, ci, wave * 512 + t * 16);
            cur ^= 1;
        }

        // reduce over the 4 quad-lanes holding the same token (disjoint cw):
        // 2 shuffle steps. Tie-break: lowest index, matching jnp.argmin.
#define REDUCE(BV, BI) {                                                          \
        _Pragma("unroll")                                                         \
        for (int mask = 16; mask <= 32; mask <<= 1) {                             \
            float ov = __shfl_xor(BV, mask, 64);                                  \
            int   oi = __shfl_xor(BI, mask, 64);                                  \
            if (ov > BV || (ov == BV && oi < BI)) { BV = ov; BI = oi; }           \
        }                                                                         \
    }
        REDUCE(bv0, bi0); REDUCE(bv1, bi1); REDUCE(bv2, bi2); REDUCE(bv3, bi3);

        // ---- cross-wave merge: each lane publishes its token's winner; one
        // raw barrier (lgkm drain only -- vmem prefetch stays in flight);
        // then merge the partner wave's half-codebook winner per set.
        // Wave 0 owns cw [0,512): equal-value tie resolves to lower index.
        {
            const int par = q & 1;
            const float myBv = (quad == 0) ? bv0 : (quad == 1) ? bv1
                             : (quad == 2) ? bv2 : bv3;
            const int   myBi = (quad == 0) ? bi0 : (quad == 1) ? bi1
                             : (quad == 2) ? bi2 : bi3;
            mrgv[par][wave][lane] = myBv;
            mrgi[par][wave][lane] = myBi;
            asm volatile("s_waitcnt lgkmcnt(0)\n\ts_barrier" ::: "memory");
            const int ow = wave ^ 1;
            float ov; int oi;
            ov = mrgv[par][ow][ 0 + m]; oi = mrgi[par][ow][ 0 + m];
            if (ov > bv0 || (ov == bv0 && oi < bi0)) { bv0 = ov; bi0 = oi; }
            ov = mrgv[par][ow][16 + m]; oi = mrgi[par][ow][16 + m];
            if (ov > bv1 || (ov == bv1 && oi < bi1)) { bv1 = ov; bi1 = oi; }
            ov = mrgv[par][ow][32 + m]; oi = mrgi[par][ow][32 + m];
            if (ov > bv2 || (ov == bv2 && oi < bi2)) { bv2 = ov; bi2 = oi; }
            ov = mrgv[par][ow][48 + m]; oi = mrgi[par][ow][48 + m];
            if (ov > bv3 || (ov == bv3 && oi < bi3)) { bv3 = ov; bi3 = oi; }
        }

        // index writes (wave 0 only; winners are now block-global)
        if (wave == 0) {
            const int myTok = tokenBase + quad * 16 + m;
            const int mybi  = (quad == 0) ? bi0 : (quad == 1) ? bi1
                            : (quad == 2) ? bi2 : bi3;
            out[(size_t)N_TOK * DIM + (size_t)myTok * QS + q] = (float)mybi;
        }

        // residual update per set (BOTH waves, identical -> registers coherent)
        float ls = 0.f;
#define RESID(BI, TH0, TH1, TL0, TL1, TS0, TS1) {                                 \
        const float* cp = cfq + (size_t)(BI) * DIM + quad * 8;                    \
        f32x4 c0 = *(const f32x4*)(cp);                                           \
        f32x4 c1 = *(const f32x4*)(cp + 4);                                       \
        f32x4 c2 = *(const f32x4*)(cp + 32);                                      \
        f32x4 c3 = *(const f32x4*)(cp + 36);                                      \
        _Pragma("unroll")                                                         \
        for (int j = 0; j < 4; ++j) {                                             \
            float v0 = fmaf(RISCALE, (float)TL0[j],   (float)TH0[j])   - c0[j];   \
            float v1 = fmaf(RISCALE, (float)TL0[j+4], (float)TH0[j+4]) - c1[j];   \
            float v2 = fmaf(RISCALE, (float)TL1[j],   (float)TH1[j])   - c2[j];   \
            float v3 = fmaf(RISCALE, (float)TL1[j+4], (float)TH1[j+4]) - c3[j];   \
            ls = fmaf(v0, v0, ls); ls = fmaf(v1, v1, ls);                         \
            ls = fmaf(v2, v2, ls); ls = fmaf(v3, v3, ls);                         \
            SPLIT3(v0, TH0[j],   TL0[j],   TS0[j]);                               \
            SPLIT3(v1, TH0[j+4], TL0[j+4], TS0[j+4]);                             \
            SPLIT3(v2, TH1[j],   TL1[j],   TS1[j]);                               \
            SPLIT3(v3, TH1[j+4], TL1[j+4], TS1[j+4]);                             \
        }                                                                         \
    }
        RESID(bi0, th00, th01, tl00, tl01, ts00, ts01);
        RESID(bi1, th10, th11, tl10, tl11, ts10, ts11);
        RESID(bi2, th20, th21, tl20, tl21, ts20, ts21);
        RESID(bi3, th30, th31, tl30, tl31, ts30, ts31);

#pragma unroll
        for (int mask = 1; mask <= 32; mask <<= 1) ls += __shfl_xor(ls, mask, 64);
        if (wave == 0 && lane == 0)
            atomicAdd(out + (size_t)N_TOK * DIM + (size_t)N_TOK * QS + q,
                      ls * (1.0f / ((float)N_TOK * (float)DIM)));
    }

    // xq = x - r_final (wave 0 only; both waves hold identical limbs)
#define XQW(S, TH0, TH1, TL0, TL1) {                                              \
        const size_t ra = (size_t)(tokenBase + (S) * 16 + m) * DIM + quad * 8;    \
        f32x4 a0 = *(const f32x4*)(x + ra);                                       \
        f32x4 a1 = *(const f32x4*)(x + ra + 4);                                   \
        f32x4 a2 = *(const f32x4*)(x + ra + 32);                                  \
        f32x4 a3 = *(const f32x4*)(x + ra + 36);                                  \
        _Pragma("unroll")                                                         \
        for (int j = 0; j < 4; ++j) {                                             \
            a0[j] -= fmaf(RISCALE, (float)TL0[j],   (float)TH0[j]);               \
            a1[j] -= fmaf(RISCALE, (float)TL0[j+4], (float)TH0[j+4]);             \
            a2[j] -= fmaf(RISCALE, (float)TL1[j],   (float)TH1[j]);               \
            a3[j] -= fmaf(RISCALE, (float)TL1[j+4], (float)TH1[j+4]);             \
        }                                                                         \
        __builtin_nontemporal_store(a0, (f32x4*)(out + ra));                      \
        __builtin_nontemporal_store(a1, (f32x4*)(out + ra + 4));                  \
        __builtin_nontemporal_store(a2, (f32x4*)(out + ra + 32));                 \
        __builtin_nontemporal_store(a3, (f32x4*)(out + ra + 36));                 \
    }
    if (wave == 0) {
        XQW(0, th00, th01, tl00, tl01);
        XQW(1, th10, th11, tl10, tl11);
        XQW(2, th20, th21, tl20, tl21);
        XQW(3, th30, th31, tl30, tl31);
    }

#undef COMPUTE
#undef STAGE
#undef LOADTOK
#undef REDUCE
#undef RESID
#undef XQW
}

extern "C" void kernel_launch(void* const* d_in, const int* in_sizes, int n_in,
                              void* d_out, int out_size, void* d_ws, size_t ws_size,
                              hipStream_t stream) {
    const float* x   = (const float*)d_in[0];   // (N, D)
    const float* cb  = (const float*)d_in[1];   // (Q, K, D)
    float*       out = (float*)d_out;           // [xq | indices | losses]
    char*        ws  = (char*)d_ws;

    _Float16* G = (_Float16*)ws;   // 512 minis x 4160 B = 2,129,920 B (+192B overread pad)

    hipMemsetAsync(out + (size_t)N_TOK * DIM + (size_t)N_TOK * QS, 0,
                   QS * sizeof(float), stream);

    conv_kernel<<<512, 256, 0, stream>>>(cb, G);
    dc2_kernel<<<(QS * KS + 255) / 256, 256, 0, stream>>>(cb, (float*)ws);
    rvq_mfma_kernel<<<N_TOK / 64, 128, 0, stream>>>(x, cb, G, out);
}

// Round 11
// 620.125 us; speedup vs baseline: 2.1938x; 2.1938x over previous
//
#include <hip/hip_runtime.h>
#include <math.h>

#define N_TOK 131072
#define DIM   64
#define QS    8
#define KS    1024

typedef _Float16 f16x8 __attribute__((ext_vector_type(8)));
typedef float    f32x4 __attribute__((ext_vector_type(4)));

#define RSCALE   2048.0f
#define RISCALE  4.8828125e-4f   // 2^-11

// split fp32 v into f16 limbs + scaled-hi: v ~= hi + lo*2^-11 ; hs = 2048*hi (exact)
#define SPLIT3(v, hi, lo, hs) { _Float16 _h = (_Float16)(v); (hi) = _h;        \
                                (lo) = (_Float16)(((v) - (float)_h) * RSCALE); \
                                (hs) = (_Float16)((float)_h * RSCALE); }

// ---- workspace layout G: 512 minis of 16 codewords, stride 4160 B:
//   [0   .. 4095]  frag limbs: 4 sub-slots of 1KB ({h0,h1,l0,l1} = limb*2+half)
//   [4096.. 4159]  16 floats: -1024*||c||^2 seeds for the mini's 16 codewords
// Mini g: stage q = g>>6, wave w = (g>>5)&1, t = g&31 -> cw w*512+t*16 .. +15.
// (The staged seed load reads 256B from +4096, overrunning 192B into the next
//  mini -- harmless garbage in LDS lanes 16-63, never read.)
#define MINI_B     4160
#define MINI_LDS_H 2176     // halves per LDS mini buffer (4096 frag + 256 seed)
#define SEED_H     2048     // half-offset of seed region in LDS buffer

// ---- pre-pass 1: codebook -> f16 limbs in MFMA A-fragment order.
// slot = mini*4 + sub; sub = limb*2 + half. Frag: [cw=lane&15][k=half*32+quad*8+j].
__global__ void conv_kernel(const float* __restrict__ cb, _Float16* __restrict__ G) {
    int t = blockIdx.x * blockDim.x + threadIdx.x;
    if (t >= 2048 * 64) return;
    const int lane = t & 63, slot = t >> 6;
    const int mini = slot >> 2, sub = slot & 3;
    const int h = sub & 1, l = sub >> 1;
    const int q = mini >> 6, idx = mini & 63, w = idx >> 5, tt = idx & 31;
    const int cw = w * 512 + tt * 16 + (lane & 15);
    const int d0 = h * 32 + (lane >> 4) * 8;
    const float* src = cb + ((size_t)q * KS + cw) * DIM + d0;
    f16x8 v;
#pragma unroll
    for (int j = 0; j < 8; ++j) {
        float c = src[j];
        _Float16 hi = (_Float16)c;
        v[j] = (l == 0) ? hi : (_Float16)((c - (float)hi) * RSCALE);
    }
    *(f16x8*)(G + (size_t)mini * 2080 + sub * 512 + lane * 8) = v;
}

// ---- pre-pass 2: dc2 seeds into each mini's tail ----
__global__ void dc2_kernel(const float* __restrict__ cb, float* __restrict__ Gf) {
    int i = blockIdx.x * blockDim.x + threadIdx.x;
    if (i < QS * KS) {
        const float* c = cb + (size_t)i * DIM;
        float s = 0.f;
#pragma unroll
        for (int d = 0; d < DIM; ++d) s = fmaf(c[d], c[d], s);
        const int q = i >> 10, k = i & 1023;
        const int w = k >> 9, tt = (k >> 4) & 31, j = k & 15;
        const int mini = q * 64 + w * 32 + tt;
        Gf[(size_t)mini * 1040 + 1024 + j] = -1024.0f * s;
    }
}

// ---- main: CODEBOOK-SPLIT 2-wave blocks (r10 structure, r10 spill fixed).
// 2048 blocks x 128 thr; both waves hold the SAME 64 tokens (4-set reuse);
// wave w scans cw [w*512,(w+1)*512) per stage via private double-buffered
// 16-cw minis (counted vmcnt(5), no intra-loop barriers).
// KEY FIX vs r10: __launch_bounds__(128, 2) -- VGPR cap 256, so the 96-VGPR
// token-limb state stays in registers (r10's (128,4) forced a 64-VGPR cap ->
// full spill -> 1.96GB scratch FETCH). Occupancy is now LDS-capped instead:
// 18.4KB/block -> exactly 8 blocks/CU = 16 waves/CU = 4 waves/SIMD, doubling
// the per-SIMD MFMA duty sum that pinned r8/r9 at 50% MfmaUtil.
__global__ __launch_bounds__(128, 2)
void rvq_mfma_kernel(const float* __restrict__ x,
                     const float* __restrict__ cbf,
                     const _Float16* __restrict__ F,
                     float* __restrict__ out) {
    __shared__ __attribute__((aligned(16))) _Float16 smem[2][2][MINI_LDS_H]; // 17408 B
    __shared__ float mrgv[2][64];   // [wave][token] 512 B (single-buffer + barrier)
    __shared__ int   mrgi[2][64];   // 512 B

    const int tid  = threadIdx.x;
    const int wave = tid >> 6;
    const int lane = tid & 63;
    const int quad = lane >> 4;
    const int m    = lane & 15;
    const int quad4 = quad * 4;

    const int tokenBase = blockIdx.x * 64;   // both waves: same 64 tokens

    // token limbs, 4 sets (B-frag layout): th = hi, tl = 2048*(r-hi), ts = 2048*hi
    f16x8 th00, th01, tl00, tl01, ts00, ts01;
    f16x8 th10, th11, tl10, tl11, ts10, ts11;
    f16x8 th20, th21, tl20, tl21, ts20, ts21;
    f16x8 th30, th31, tl30, tl31, ts30, ts31;

#define LOADTOK(S, TH0, TH1, TL0, TL1, TS0, TS1) {                                \
        const float* xa = x + (size_t)(tokenBase + (S) * 16 + m) * DIM + quad * 8;\
        f32x4 a0 = *(const f32x4*)(xa);                                           \
        f32x4 a1 = *(const f32x4*)(xa + 4);                                       \
        f32x4 a2 = *(const f32x4*)(xa + 32);                                      \
        f32x4 a3 = *(const f32x4*)(xa + 36);                                      \
        _Pragma("unroll")                                                         \
        for (int j = 0; j < 4; ++j) {                                             \
            SPLIT3(a0[j], TH0[j],   TL0[j],   TS0[j]);                            \
            SPLIT3(a1[j], TH0[j+4], TL0[j+4], TS0[j+4]);                          \
            SPLIT3(a2[j], TH1[j],   TL1[j],   TS1[j]);                            \
            SPLIT3(a3[j], TH1[j+4], TL1[j+4], TS1[j+4]);                          \
        }                                                                         \
    }
    LOADTOK(0, th00, th01, tl00, tl01, ts00, ts01);
    LOADTOK(1, th10, th11, tl10, tl11, ts10, ts11);
    LOADTOK(2, th20, th21, tl20, tl21, ts20, ts21);
    LOADTOK(3, th30, th31, tl30, tl31, ts30, ts31);

// stage one 16-cw mini (4KB frags + seed) into this wave's LDS buffer BUF.
// 5 vmem ops total.
#define STAGE(GC, BUF) {                                                          \
        const char* _gs = (const char*)F + (size_t)(GC) * MINI_B + (lane << 4);   \
        _Float16* _ld = &smem[wave][BUF][0];                                      \
        _Pragma("unroll")                                                         \
        for (int _j = 0; _j < 4; ++_j)                                            \
            __builtin_amdgcn_global_load_lds(                                     \
                (const __attribute__((address_space(1))) void*)(_gs + _j * 1024), \
                (__attribute__((address_space(3))) void*)(_ld + _j * 512),        \
                16, 0, 0);                                                        \
        __builtin_amdgcn_global_load_lds(                                         \
            (const __attribute__((address_space(1))) void*)((const char*)F        \
                + (size_t)(GC) * MINI_B + 4096 + (lane << 2)),                    \
            (__attribute__((address_space(3))) void*)(_ld + SEED_H),              \
            4, 0, 0);                                                             \
    }

// One 16-cw group: 24 MFMAs = 4 independent depth-6 chains (one per token-set),
// all sharing the codeword fragments. acc IS the scaled score.
#define COMPUTE(CH0, CH1, CL0, CL1, CIV, CWB) {                                     \
        __builtin_amdgcn_s_setprio(1);                                              \
        f32x4 A0 = __builtin_amdgcn_mfma_f32_16x16x32_f16(CH0, ts00, CIV, 0,0,0);   \
        f32x4 A1 = __builtin_amdgcn_mfma_f32_16x16x32_f16(CH0, ts10, CIV, 0,0,0);   \
        f32x4 A2 = __builtin_amdgcn_mfma_f32_16x16x32_f16(CH0, ts20, CIV, 0,0,0);   \
        f32x4 A3 = __builtin_amdgcn_mfma_f32_16x16x32_f16(CH0, ts30, CIV, 0,0,0);   \
        A0 = __builtin_amdgcn_mfma_f32_16x16x32_f16(CH1, ts01, A0, 0,0,0);          \
        A1 = __builtin_amdgcn_mfma_f32_16x16x32_f16(CH1, ts11, A1, 0,0,0);          \
        A2 = __builtin_amdgcn_mfma_f32_16x16x32_f16(CH1, ts21, A2, 0,0,0);          \
        A3 = __builtin_amdgcn_mfma_f32_16x16x32_f16(CH1, ts31, A3, 0,0,0);          \
        A0 = __builtin_amdgcn_mfma_f32_16x16x32_f16(CL0, th00, A0, 0,0,0);          \
        A1 = __builtin_amdgcn_mfma_f32_16x16x32_f16(CL0, th10, A1, 0,0,0);          \
        A2 = __builtin_amdgcn_mfma_f32_16x16x32_f16(CL0, th20, A2, 0,0,0);          \
        A3 = __builtin_amdgcn_mfma_f32_16x16x32_f16(CL0, th30, A3, 0,0,0);          \
        A0 = __builtin_amdgcn_mfma_f32_16x16x32_f16(CL1, th01, A0, 0,0,0);          \
        A1 = __builtin_amdgcn_mfma_f32_16x16x32_f16(CL1, th11, A1, 0,0,0);          \
        A2 = __builtin_amdgcn_mfma_f32_16x16x32_f16(CL1, th21, A2, 0,0,0);          \
        A3 = __builtin_amdgcn_mfma_f32_16x16x32_f16(CL1, th31, A3, 0,0,0);          \
        A0 = __builtin_amdgcn_mfma_f32_16x16x32_f16(CH0, tl00, A0, 0,0,0);          \
        A1 = __builtin_amdgcn_mfma_f32_16x16x32_f16(CH0, tl10, A1, 0,0,0);          \
        A2 = __builtin_amdgcn_mfma_f32_16x16x32_f16(CH0, tl20, A2, 0,0,0);          \
        A3 = __builtin_amdgcn_mfma_f32_16x16x32_f16(CH0, tl30, A3, 0,0,0);          \
        A0 = __builtin_amdgcn_mfma_f32_16x16x32_f16(CH1, tl01, A0, 0,0,0);          \
        A1 = __builtin_amdgcn_mfma_f32_16x16x32_f16(CH1, tl11, A1, 0,0,0);          \
        A2 = __builtin_amdgcn_mfma_f32_16x16x32_f16(CH1, tl21, A2, 0,0,0);          \
        A3 = __builtin_amdgcn_mfma_f32_16x16x32_f16(CH1, tl31, A3, 0,0,0);          \
        __builtin_amdgcn_s_setprio(0);                                              \
        const int base = (CWB) + quad4;                                             \
        _Pragma("unroll")                                                           \
        for (int i = 0; i < 4; ++i) {                                               \
            if (A0[i] > bv0) { bv0 = A0[i]; bi0 = base + i; }                       \
            if (A1[i] > bv1) { bv1 = A1[i]; bi1 = base + i; }                       \
            if (A2[i] > bv2) { bv2 = A2[i]; bi2 = base + i; }                       \
            if (A3[i] > bv3) { bv3 = A3[i]; bi3 = base + i; }                       \
        }                                                                           \
    }

    // prologue: stage this wave's first mini of stage 0
    STAGE(wave * 32, 0);
    int cur = 0;

    for (int q = 0; q < QS; ++q) {
        const float* cfq = cbf + (size_t)q * KS * DIM;

        float bv0 = -INFINITY, bv1 = -INFINITY, bv2 = -INFINITY, bv3 = -INFINITY;
        int   bi0 = 0, bi1 = 0, bi2 = 0, bi3 = 0;

        for (int t = 0; t < 32; ++t) {
            int nxt = (t < 31) ? (q * 64 + wave * 32 + t + 1)
                    : (q < 7)  ? ((q + 1) * 64 + wave * 32) : -1;
            if (nxt >= 0) {
                STAGE(nxt, cur ^ 1);   // 5 vmem ops
                // wait until only the 5 just-issued remain -> current mini
                // (and everything older) resident. Never drains the prefetch.
                asm volatile("s_waitcnt vmcnt(5)" ::: "memory");
            } else {
                asm volatile("s_waitcnt vmcnt(0)" ::: "memory");
            }
            __builtin_amdgcn_sched_barrier(0);

            const _Float16* L   = &smem[wave][cur][0] + lane * 8;
            const float*    dcL = (const float*)(&smem[wave][cur][SEED_H]);

            f32x4 ci = *(const f32x4*)(dcL + quad4);
            f16x8 h0 = *(const f16x8*)(L);
            f16x8 h1 = *(const f16x8*)(L + 512);
            f16x8 l0 = *(const f16x8*)(L + 1024);
            f16x8 l1 = *(const f16x8*)(L + 1536);

            COMPUTE(h0, h1, l0, l1, ci, wave * 512 + t * 16);
            cur ^= 1;
        }

        // reduce over the 4 quad-lanes holding the same token (disjoint cw):
        // 2 shuffle steps. Tie-break: lowest index, matching jnp.argmin.
#define REDUCE(BV, BI) {                                                          \
        _Pragma("unroll")                                                         \
        for (int mask = 16; mask <= 32; mask <<= 1) {                             \
            float ov = __shfl_xor(BV, mask, 64);                                  \
            int   oi = __shfl_xor(BI, mask, 64);                                  \
            if (ov > BV || (ov == BV && oi < BI)) { BV = ov; BI = oi; }           \
        }                                                                         \
    }
        REDUCE(bv0, bi0); REDUCE(bv1, bi1); REDUCE(bv2, bi2); REDUCE(bv3, bi3);

        // ---- cross-wave merge: each lane publishes its token's winner; raw
        // barrier (lgkm drain only -- vmem prefetch stays in flight); merge the
        // partner wave's half-codebook winner per set; second raw barrier
        // before the buffers can be rewritten next stage.
        // Wave 0 owns cw [0,512): equal-value tie resolves to lower index.
        {
            const float myBv = (quad == 0) ? bv0 : (quad == 1) ? bv1
                             : (quad == 2) ? bv2 : bv3;
            const int   myBi = (quad == 0) ? bi0 : (quad == 1) ? bi1
                             : (quad == 2) ? bi2 : bi3;
            mrgv[wave][lane] = myBv;
            mrgi[wave][lane] = myBi;
            asm volatile("s_waitcnt lgkmcnt(0)\n\ts_barrier" ::: "memory");
            const int ow = wave ^ 1;
            float ov; int oi;
            ov = mrgv[ow][ 0 + m]; oi = mrgi[ow][ 0 + m];
            if (ov > bv0 || (ov == bv0 && oi < bi0)) { bv0 = ov; bi0 = oi; }
            ov = mrgv[ow][16 + m]; oi = mrgi[ow][16 + m];
            if (ov > bv1 || (ov == bv1 && oi < bi1)) { bv1 = ov; bi1 = oi; }
            ov = mrgv[ow][32 + m]; oi = mrgi[ow][32 + m];
            if (ov > bv2 || (ov == bv2 && oi < bi2)) { bv2 = ov; bi2 = oi; }
            ov = mrgv[ow][48 + m]; oi = mrgi[ow][48 + m];
            if (ov > bv3 || (ov == bv3 && oi < bi3)) { bv3 = ov; bi3 = oi; }
            asm volatile("s_waitcnt lgkmcnt(0)\n\ts_barrier" ::: "memory");
        }

        // index writes (wave 0 only; winners are now block-global)
        if (wave == 0) {
            const int myTok = tokenBase + quad * 16 + m;
            const int mybi  = (quad == 0) ? bi0 : (quad == 1) ? bi1
                            : (quad == 2) ? bi2 : bi3;
            out[(size_t)N_TOK * DIM + (size_t)myTok * QS + q] = (float)mybi;
        }

        // residual update per set (BOTH waves, identical -> registers coherent)
        float ls = 0.f;
#define RESID(BI, TH0, TH1, TL0, TL1, TS0, TS1) {                                 \
        const float* cp = cfq + (size_t)(BI) * DIM + quad * 8;                    \
        f32x4 c0 = *(const f32x4*)(cp);                                           \
        f32x4 c1 = *(const f32x4*)(cp + 4);                                       \
        f32x4 c2 = *(const f32x4*)(cp + 32);                                      \
        f32x4 c3 = *(const f32x4*)(cp + 36);                                      \
        _Pragma("unroll")                                                         \
        for (int j = 0; j < 4; ++j) {                                             \
            float v0 = fmaf(RISCALE, (float)TL0[j],   (float)TH0[j])   - c0[j];   \
            float v1 = fmaf(RISCALE, (float)TL0[j+4], (float)TH0[j+4]) - c1[j];   \
            float v2 = fmaf(RISCALE, (float)TL1[j],   (float)TH1[j])   - c2[j];   \
            float v3 = fmaf(RISCALE, (float)TL1[j+4], (float)TH1[j+4]) - c3[j];   \
            ls = fmaf(v0, v0, ls); ls = fmaf(v1, v1, ls);                         \
            ls = fmaf(v2, v2, ls); ls = fmaf(v3, v3, ls);                         \
            SPLIT3(v0, TH0[j],   TL0[j],   TS0[j]);                               \
            SPLIT3(v1, TH0[j+4], TL0[j+4], TS0[j+4]);                             \
            SPLIT3(v2, TH1[j],   TL1[j],   TS1[j]);                               \
            SPLIT3(v3, TH1[j+4], TL1[j+4], TS1[j+4]);                             \
        }                                                                         \
    }
        RESID(bi0, th00, th01, tl00, tl01, ts00, ts01);
        RESID(bi1, th10, th11, tl10, tl11, ts10, ts11);
        RESID(bi2, th20, th21, tl20, tl21, ts20, ts21);
        RESID(bi3, th30, th31, tl30, tl31, ts30, ts31);

#pragma unroll
        for (int mask = 1; mask <= 32; mask <<= 1) ls += __shfl_xor(ls, mask, 64);
        if (wave == 0 && lane == 0)
            atomicAdd(out + (size_t)N_TOK * DIM + (size_t)N_TOK * QS + q,
                      ls * (1.0f / ((float)N_TOK * (float)DIM)));
    }

    // xq = x - r_final (wave 0 only; both waves hold identical limbs)
#define XQW(S, TH0, TH1, TL0, TL1) {                                              \
        const size_t ra = (size_t)(tokenBase + (S) * 16 + m) * DIM + quad * 8;    \
        f32x4 a0 = *(const f32x4*)(x + ra);                                       \
        f32x4 a1 = *(const f32x4*)(x + ra + 4);                                   \
        f32x4 a2 = *(const f32x4*)(x + ra + 32);                                  \
        f32x4 a3 = *(const f32x4*)(x + ra + 36);                                  \
        _Pragma("unroll")                                                         \
        for (int j = 0; j < 4; ++j) {                                             \
            a0[j] -= fmaf(RISCALE, (float)TL0[j],   (float)TH0[j]);               \
            a1[j] -= fmaf(RISCALE, (float)TL0[j+4], (float)TH0[j+4]);             \
            a2[j] -= fmaf(RISCALE, (float)TL1[j],   (float)TH1[j]);               \
            a3[j] -= fmaf(RISCALE, (float)TL1[j+4], (float)TH1[j+4]);             \
        }                                                                         \
        __builtin_nontemporal_store(a0, (f32x4*)(out + ra));                      \
        __builtin_nontemporal_store(a1, (f32x4*)(out + ra + 4));                  \
        __builtin_nontemporal_store(a2, (f32x4*)(out + ra + 32));                 \
        __builtin_nontemporal_store(a3, (f32x4*)(out + ra + 36));                 \
    }
    if (wave == 0) {
        XQW(0, th00, th01, tl00, tl01);
        XQW(1, th10, th11, tl10, tl11);
        XQW(2, th20, th21, tl20, tl21);
        XQW(3, th30, th31, tl30, tl31);
    }

#undef COMPUTE
#undef STAGE
#undef LOADTOK
#undef REDUCE
#undef RESID
#undef XQW
}

extern "C" void kernel_launch(void* const* d_in, const int* in_sizes, int n_in,
                              void* d_out, int out_size, void* d_ws, size_t ws_size,
                              hipStream_t stream) {
    const float* x   = (const float*)d_in[0];   // (N, D)
    const float* cb  = (const float*)d_in[1];   // (Q, K, D)
    float*       out = (float*)d_out;           // [xq | indices | losses]
    char*        ws  = (char*)d_ws;

    _Float16* G = (_Float16*)ws;   // 512 minis x 4160 B = 2,129,920 B (+192B overread pad)

    hipMemsetAsync(out + (size_t)N_TOK * DIM + (size_t)N_TOK * QS, 0,
                   QS * sizeof(float), stream);

    conv_kernel<<<512, 256, 0, stream>>>(cb, G);
    dc2_kernel<<<(QS * KS + 255) / 256, 256, 0, stream>>>(cb, (float*)ws);
    rvq_mfma_kernel<<<N_TOK / 64, 128, 0, stream>>>(x, cb, G, out);
}

// Round 12
// 438.767 us; speedup vs baseline: 3.1006x; 1.4133x over previous
//
#include <hip/hip_runtime.h>
#include <math.h>

#define N_TOK 131072
#define DIM   64
#define QS    8
#define KS    1024

typedef _Float16 f16x8 __attribute__((ext_vector_type(8)));
typedef float    f32x4 __attribute__((ext_vector_type(4)));

#define RSCALE   2048.0f
#define RISCALE  4.8828125e-4f   // 2^-11

// split fp32 v into f16 limbs + scaled-hi: v ~= hi + lo*2^-11 ; hs = 2048*hi (exact)
#define SPLIT3(v, hi, lo, hs) { _Float16 _h = (_Float16)(v); (hi) = _h;        \
                                (lo) = (_Float16)(((v) - (float)_h) * RSCALE); \
                                (hs) = (_Float16)((float)_h * RSCALE); }

// ---- workspace layout G: 128 chunks, each 16640 B:
//   [0    .. 16383]  frag limbs: 16 sub-slots of 1KB (4 groups x {h0,h1,l0,l1})
//   [16384.. 16639]  64 floats: -1024*||c||^2 seeds for the chunk's 64 codewords
// Chunk c covers stage q = c>>4, codewords (c&15)*64 .. +63.

// ---- pre-pass 1: codebook -> f16 limbs in MFMA fragment order.
// slot = (q*64+g)*4 + l*2 + h ; chunk c = slot>>4, sub = slot&15.
__global__ void conv_kernel(const float* __restrict__ cb, _Float16* __restrict__ G) {
    int t = blockIdx.x * blockDim.x + threadIdx.x;
    if (t >= 2048 * 64) return;
    const int lane = t & 63, slot = t >> 6;
    const int h = slot & 1, l = (slot >> 1) & 1, g = (slot >> 2) & 63, q = slot >> 8;
    const int cw = g * 16 + (lane & 15);
    const int d0 = h * 32 + (lane >> 4) * 8;
    const float* src = cb + ((size_t)q * KS + cw) * DIM + d0;
    f16x8 v;
#pragma unroll
    for (int j = 0; j < 8; ++j) {
        float c = src[j];
        _Float16 hi = (_Float16)c;
        v[j] = (l == 0) ? hi : (_Float16)((c - (float)hi) * RSCALE);
    }
    const int c = slot >> 4, w = slot & 15;
    *(f16x8*)(G + (size_t)c * 8320 + w * 512 + lane * 8) = v;
}

// ---- pre-pass 2: dc2 seeds written straight into each chunk's tail ----
__global__ void dc2_kernel(const float* __restrict__ cb, float* __restrict__ Gf) {
    int i = blockIdx.x * blockDim.x + threadIdx.x;
    if (i < QS * KS) {
        const float* c = cb + (size_t)i * DIM;
        float s = 0.f;
#pragma unroll
        for (int d = 0; d < DIM; ++d) s = fmaf(c[d], c[d], s);
        const int q = i >> 10, k = i & 1023;
        const int ch = q * 16 + (k >> 6), j = k & 63;
        Gf[(size_t)ch * 4160 + 4096 + j] = -1024.0f * s;
    }
}

#define CHUNK_B   16640     // bytes per chunk (16KB frags + 256B dc2)
#define CHUNK_H   8320      // _Float16 elements per chunk
#define DC2_OFF_H 8192      // half-offset of dc2 region (byte 16384)

// ---- main: r6 structure with 2-WAVE BLOCKS. 1024 blocks x 128 thr; each wave
// owns 64 tokens (4 token-sets, r6 reuse intact); both waves share the staged
// chunk double-buffer (33.3KB LDS). r6 was GRID-limited to 2 blocks/CU; this
// grid gives 4 blocks/CU x 2 waves = 16 waves/CU = 4 waves/SIMD -- double
// r6/r8's 2/SIMD, which capped MfmaUtil at ~50% (per-wave duty ~25%).
// Per-token math byte-identical to r6/r8.
__global__ __launch_bounds__(128, 2)
void rvq_mfma_kernel(const float* __restrict__ x,
                     const float* __restrict__ cbf,
                     const _Float16* __restrict__ F,
                     float* __restrict__ out) {
    __shared__ __attribute__((aligned(16))) _Float16 smem[2 * CHUNK_H]; // 33.3 KB

    const int tid  = threadIdx.x;
    const int wave = tid >> 6;
    const int lane = tid & 63;
    const int quad = lane >> 4;
    const int m    = lane & 15;
    const int quad4 = quad * 4;

    const int tokenBase = blockIdx.x * 128 + wave * 64;

    // token limbs, 4 sets (B-frag layout): th = hi, tl = 2048*(r-hi), ts = 2048*hi
    f16x8 th00, th01, tl00, tl01, ts00, ts01;
    f16x8 th10, th11, tl10, tl11, ts10, ts11;
    f16x8 th20, th21, tl20, tl21, ts20, ts21;
    f16x8 th30, th31, tl30, tl31, ts30, ts31;

#define LOADTOK(S, TH0, TH1, TL0, TL1, TS0, TS1) {                                \
        const float* xa = x + (size_t)(tokenBase + (S) * 16 + m) * DIM + quad * 8;\
        f32x4 a0 = __builtin_nontemporal_load((const f32x4*)(xa));                \
        f32x4 a1 = __builtin_nontemporal_load((const f32x4*)(xa + 4));            \
        f32x4 a2 = __builtin_nontemporal_load((const f32x4*)(xa + 32));           \
        f32x4 a3 = __builtin_nontemporal_load((const f32x4*)(xa + 36));           \
        _Pragma("unroll")                                                         \
        for (int j = 0; j < 4; ++j) {                                             \
            SPLIT3(a0[j], TH0[j],   TL0[j],   TS0[j]);                            \
            SPLIT3(a1[j], TH0[j+4], TL0[j+4], TS0[j+4]);                          \
            SPLIT3(a2[j], TH1[j],   TL1[j],   TS1[j]);                            \
            SPLIT3(a3[j], TH1[j+4], TL1[j+4], TS1[j+4]);                          \
        }                                                                         \
    }
    LOADTOK(0, th00, th01, tl00, tl01, ts00, ts01);
    LOADTOK(1, th10, th11, tl10, tl11, ts10, ts11);
    LOADTOK(2, th20, th21, tl20, tl21, ts20, ts21);
    LOADTOK(3, th30, th31, tl30, tl31, ts30, ts31);

// stage one full chunk (frags + dc2 tail) of G into LDS buffer BUF.
// 2 waves: wave w covers bytes [w*8192, (w+1)*8192) as 8 x 1KB ops;
// wave 0 additionally stages the 256B dc2 tail. dest = wave-uniform base.
#define STAGE(GC, BUF) {                                                          \
        const char* _gs = (const char*)F + (size_t)(GC) * CHUNK_B                 \
                          + (wave << 13) + (lane << 4);                           \
        _Float16* _ld = smem + (BUF) * CHUNK_H + (wave << 12);                    \
        _Pragma("unroll")                                                         \
        for (int _j = 0; _j < 8; ++_j)                                            \
            __builtin_amdgcn_global_load_lds(                                     \
                (const __attribute__((address_space(1))) void*)(_gs + _j * 1024), \
                (__attribute__((address_space(3))) void*)(_ld + _j * 512),        \
                16, 0, 0);                                                        \
        if (wave == 0) {                                                          \
            const char* _gd = (const char*)F + (size_t)(GC) * CHUNK_B + 16384     \
                              + (lane << 2);                                      \
            __builtin_amdgcn_global_load_lds(                                     \
                (const __attribute__((address_space(1))) void*)_gd,               \
                (__attribute__((address_space(3))) void*)(smem + (BUF) * CHUNK_H  \
                                                          + DC2_OFF_H),           \
                4, 0, 0);                                                         \
        }                                                                         \
    }

// One group: 24 MFMAs = 4 independent depth-6 chains (one per token-set),
// all sharing the same codeword fragments. acc IS the scaled score.
#define COMPUTE(CH0, CH1, CL0, CL1, CIV, G) {                                       \
        __builtin_amdgcn_s_setprio(1);                                              \
        f32x4 A0 = __builtin_amdgcn_mfma_f32_16x16x32_f16(CH0, ts00, CIV, 0,0,0);   \
        f32x4 A1 = __builtin_amdgcn_mfma_f32_16x16x32_f16(CH0, ts10, CIV, 0,0,0);   \
        f32x4 A2 = __builtin_amdgcn_mfma_f32_16x16x32_f16(CH0, ts20, CIV, 0,0,0);   \
        f32x4 A3 = __builtin_amdgcn_mfma_f32_16x16x32_f16(CH0, ts30, CIV, 0,0,0);   \
        A0 = __builtin_amdgcn_mfma_f32_16x16x32_f16(CH1, ts01, A0, 0,0,0);          \
        A1 = __builtin_amdgcn_mfma_f32_16x16x32_f16(CH1, ts11, A1, 0,0,0);          \
        A2 = __builtin_amdgcn_mfma_f32_16x16x32_f16(CH1, ts21, A2, 0,0,0);          \
        A3 = __builtin_amdgcn_mfma_f32_16x16x32_f16(CH1, ts31, A3, 0,0,0);          \
        A0 = __builtin_amdgcn_mfma_f32_16x16x32_f16(CL0, th00, A0, 0,0,0);          \
        A1 = __builtin_amdgcn_mfma_f32_16x16x32_f16(CL0, th10, A1, 0,0,0);          \
        A2 = __builtin_amdgcn_mfma_f32_16x16x32_f16(CL0, th20, A2, 0,0,0);          \
        A3 = __builtin_amdgcn_mfma_f32_16x16x32_f16(CL0, th30, A3, 0,0,0);          \
        A0 = __builtin_amdgcn_mfma_f32_16x16x32_f16(CL1, th01, A0, 0,0,0);          \
        A1 = __builtin_amdgcn_mfma_f32_16x16x32_f16(CL1, th11, A1, 0,0,0);          \
        A2 = __builtin_amdgcn_mfma_f32_16x16x32_f16(CL1, th21, A2, 0,0,0);          \
        A3 = __builtin_amdgcn_mfma_f32_16x16x32_f16(CL1, th31, A3, 0,0,0);          \
        A0 = __builtin_amdgcn_mfma_f32_16x16x32_f16(CH0, tl00, A0, 0,0,0);          \
        A1 = __builtin_amdgcn_mfma_f32_16x16x32_f16(CH0, tl10, A1, 0,0,0);          \
        A2 = __builtin_amdgcn_mfma_f32_16x16x32_f16(CH0, tl20, A2, 0,0,0);          \
        A3 = __builtin_amdgcn_mfma_f32_16x16x32_f16(CH0, tl30, A3, 0,0,0);          \
        A0 = __builtin_amdgcn_mfma_f32_16x16x32_f16(CH1, tl01, A0, 0,0,0);          \
        A1 = __builtin_amdgcn_mfma_f32_16x16x32_f16(CH1, tl11, A1, 0,0,0);          \
        A2 = __builtin_amdgcn_mfma_f32_16x16x32_f16(CH1, tl21, A2, 0,0,0);          \
        A3 = __builtin_amdgcn_mfma_f32_16x16x32_f16(CH1, tl31, A3, 0,0,0);          \
        __builtin_amdgcn_s_setprio(0);                                              \
        const int base = (G) * 16 + quad4;                                          \
        _Pragma("unroll")                                                           \
        for (int i = 0; i < 4; ++i) {                                               \
            if (A0[i] > bv0) { bv0 = A0[i]; bi0 = base + i; }                       \
            if (A1[i] > bv1) { bv1 = A1[i]; bi1 = base + i; }                       \
            if (A2[i] > bv2) { bv2 = A2[i]; bi2 = base + i; }                       \
            if (A3[i] > bv3) { bv3 = A3[i]; bi3 = base + i; }                       \
        }                                                                           \
    }

    // prologue: stage chunk 0 of stage 0
    STAGE(0, 0);
    __syncthreads();
    int cur = 0;

    for (int q = 0; q < QS; ++q) {
        const float* cfq = cbf + (size_t)q * KS * DIM;

        float bv0 = -INFINITY, bv1 = -INFINITY, bv2 = -INFINITY, bv3 = -INFINITY;
        int   bi0 = 0, bi1 = 0, bi2 = 0, bi3 = 0;

        for (int ch = 0; ch < 16; ++ch) {
            const int gc = (q << 4) | ch;
            if (gc + 1 < 128) STAGE(gc + 1, cur ^ 1);   // prefetch next chunk

            const _Float16* L   = smem + cur * CHUNK_H + lane * 8;
            const float*    dcL = (const float*)(smem + cur * CHUNK_H + DC2_OFF_H);
            const int gbase = ch * 4;

            // dc2 seeds up front (broadcast within quad, no conflict)
            f32x4 ci0 = *(const f32x4*)(dcL +  0 + quad4);
            f32x4 ci1 = *(const f32x4*)(dcL + 16 + quad4);
            f32x4 ci2 = *(const f32x4*)(dcL + 32 + quad4);
            f32x4 ci3 = *(const f32x4*)(dcL + 48 + quad4);

            // register double-buffer over the chunk's 4 groups (ds_read_b128)
            f16x8 g0h0 = *(const f16x8*)(L);
            f16x8 g0h1 = *(const f16x8*)(L + 512);
            f16x8 g0l0 = *(const f16x8*)(L + 1024);
            f16x8 g0l1 = *(const f16x8*)(L + 1536);

            f16x8 g1h0 = *(const f16x8*)(L + 2048);
            f16x8 g1h1 = *(const f16x8*)(L + 2560);
            f16x8 g1l0 = *(const f16x8*)(L + 3072);
            f16x8 g1l1 = *(const f16x8*)(L + 3584);

            COMPUTE(g0h0, g0h1, g0l0, g0l1, ci0, gbase + 0);

            g0h0 = *(const f16x8*)(L + 4096);
            g0h1 = *(const f16x8*)(L + 4608);
            g0l0 = *(const f16x8*)(L + 5120);
            g0l1 = *(const f16x8*)(L + 5632);

            COMPUTE(g1h0, g1h1, g1l0, g1l1, ci1, gbase + 1);

            g1h0 = *(const f16x8*)(L + 6144);
            g1h1 = *(const f16x8*)(L + 6656);
            g1l0 = *(const f16x8*)(L + 7168);
            g1l1 = *(const f16x8*)(L + 7680);

            COMPUTE(g0h0, g0h1, g0l0, g0l1, ci2, gbase + 2);
            COMPUTE(g1h0, g1h1, g1l0, g1l1, ci3, gbase + 3);

            // barrier doubles as vmcnt/lgkm drain: staged chunk gc+1 resident,
            // both waves done reading buffer cur.
            __syncthreads();
            cur ^= 1;
        }

        // reduce over the 4 quad-lanes holding the same token (disjoint codewords):
        // 2 shuffle steps. Tie-break: lowest index, matching jnp.argmin.
#define REDUCE(BV, BI) {                                                          \
        _Pragma("unroll")                                                         \
        for (int mask = 16; mask <= 32; mask <<= 1) {                             \
            float ov = __shfl_xor(BV, mask, 64);                                  \
            int   oi = __shfl_xor(BI, mask, 64);                                  \
            if (ov > BV || (ov == BV && oi < BI)) { BV = ov; BI = oi; }           \
        }                                                                         \
    }
        REDUCE(bv0, bi0); REDUCE(bv1, bi1); REDUCE(bv2, bi2); REDUCE(bv3, bi3);

        // index writes: quad s writes set s's token (64 lanes = 64 tokens)
        {
            const int myTok = tokenBase + quad * 16 + m;
            const int mybi  = (quad == 0) ? bi0 : (quad == 1) ? bi1
                            : (quad == 2) ? bi2 : bi3;
            out[(size_t)N_TOK * DIM + (size_t)myTok * QS + q] = (float)mybi;
        }

        // residual update per set: reconstruct r, subtract fp32 codeword, re-split
        float ls = 0.f;
#define RESID(BI, TH0, TH1, TL0, TL1, TS0, TS1) {                                 \
        const float* cp = cfq + (size_t)(BI) * DIM + quad * 8;                    \
        f32x4 c0 = *(const f32x4*)(cp);                                           \
        f32x4 c1 = *(const f32x4*)(cp + 4);                                       \
        f32x4 c2 = *(const f32x4*)(cp + 32);                                      \
        f32x4 c3 = *(const f32x4*)(cp + 36);                                      \
        _Pragma("unroll")                                                         \
        for (int j = 0; j < 4; ++j) {                                             \
            float v0 = fmaf(RISCALE, (float)TL0[j],   (float)TH0[j])   - c0[j];   \
            float v1 = fmaf(RISCALE, (float)TL0[j+4], (float)TH0[j+4]) - c1[j];   \
            float v2 = fmaf(RISCALE, (float)TL1[j],   (float)TH1[j])   - c2[j];   \
            float v3 = fmaf(RISCALE, (float)TL1[j+4], (float)TH1[j+4]) - c3[j];   \
            ls = fmaf(v0, v0, ls); ls = fmaf(v1, v1, ls);                         \
            ls = fmaf(v2, v2, ls); ls = fmaf(v3, v3, ls);                         \
            SPLIT3(v0, TH0[j],   TL0[j],   TS0[j]);                               \
            SPLIT3(v1, TH0[j+4], TL0[j+4], TS0[j+4]);                             \
            SPLIT3(v2, TH1[j],   TL1[j],   TS1[j]);                               \
            SPLIT3(v3, TH1[j+4], TL1[j+4], TS1[j+4]);                             \
        }                                                                         \
    }
        RESID(bi0, th00, th01, tl00, tl01, ts00, ts01);
        RESID(bi1, th10, th11, tl10, tl11, ts10, ts11);
        RESID(bi2, th20, th21, tl20, tl21, ts20, ts21);
        RESID(bi3, th30, th31, tl30, tl31, ts30, ts31);

#pragma unroll
        for (int mask = 1; mask <= 32; mask <<= 1) ls += __shfl_xor(ls, mask, 64);
        if (lane == 0)
            atomicAdd(out + (size_t)N_TOK * DIM + (size_t)N_TOK * QS + q,
                      ls * (1.0f / ((float)N_TOK * (float)DIM)));
    }

    // xq = x - r_final (reconstruct final residual from limbs), per set
#define XQW(S, TH0, TH1, TL0, TL1) {                                              \
        const size_t ra = (size_t)(tokenBase + (S) * 16 + m) * DIM + quad * 8;    \
        f32x4 a0 = __builtin_nontemporal_load((const f32x4*)(x + ra));            \
        f32x4 a1 = __builtin_nontemporal_load((const f32x4*)(x + ra + 4));        \
        f32x4 a2 = __builtin_nontemporal_load((const f32x4*)(x + ra + 32));       \
        f32x4 a3 = __builtin_nontemporal_load((const f32x4*)(x + ra + 36));       \
        _Pragma("unroll")                                                         \
        for (int j = 0; j < 4; ++j) {                                             \
            a0[j] -= fmaf(RISCALE, (float)TL0[j],   (float)TH0[j]);               \
            a1[j] -= fmaf(RISCALE, (float)TL0[j+4], (float)TH0[j+4]);             \
            a2[j] -= fmaf(RISCALE, (float)TL1[j],   (float)TH1[j]);               \
            a3[j] -= fmaf(RISCALE, (float)TL1[j+4], (float)TH1[j+4]);             \
        }                                                                         \
        __builtin_nontemporal_store(a0, (f32x4*)(out + ra));                      \
        __builtin_nontemporal_store(a1, (f32x4*)(out + ra + 4));                  \
        __builtin_nontemporal_store(a2, (f32x4*)(out + ra + 32));                 \
        __builtin_nontemporal_store(a3, (f32x4*)(out + ra + 36));                 \
    }
    XQW(0, th00, th01, tl00, tl01);
    XQW(1, th10, th11, tl10, tl11);
    XQW(2, th20, th21, tl20, tl21);
    XQW(3, th30, th31, tl30, tl31);

#undef COMPUTE
#undef STAGE
#undef LOADTOK
#undef REDUCE
#undef RESID
#undef XQW
}

extern "C" void kernel_launch(void* const* d_in, const int* in_sizes, int n_in,
                              void* d_out, int out_size, void* d_ws, size_t ws_size,
                              hipStream_t stream) {
    const float* x   = (const float*)d_in[0];   // (N, D)
    const float* cb  = (const float*)d_in[1];   // (Q, K, D)
    float*       out = (float*)d_out;           // [xq | indices | losses]
    char*        ws  = (char*)d_ws;

    _Float16* G = (_Float16*)ws;   // 128 chunks x 16640 B = 2,129,920 B

    hipMemsetAsync(out + (size_t)N_TOK * DIM + (size_t)N_TOK * QS, 0,
                   QS * sizeof(float), stream);

    conv_kernel<<<512, 256, 0, stream>>>(cb, G);
    dc2_kernel<<<(QS * KS + 255) / 256, 256, 0, stream>>>(cb, (float*)ws);
    rvq_mfma_kernel<<<N_TOK / 128, 128, 0, stream>>>(x, cb, G, out);
}